// Round 9
// baseline (496.949 us; speedup 1.0000x reference)
//
#include <hip/hip_runtime.h>
#include <hip/hip_bf16.h>

// Problem constants: N=200000, C=128, K=32, B=16, 20 Sinkhorn iters.
#define C_DIM 128
#define K_DIM 32
#define N_ITERS 20
#define WPAD 136   // bf16 row pad: 136*2B = 272B = 68 words -> bank step 4/row (2-way = free)
#define SK_THREADS 832   // 13 waves
#define SK_WAVES 13
#define NGRP 16          // barrier tree: 16 groups x 16 blocks
#define GSIZE 16

typedef __attribute__((ext_vector_type(8))) short short8;      // 8 bf16 (4 VGPR) MFMA A/B frag
typedef __attribute__((ext_vector_type(4))) float f32x4;       // MFMA C/D frag
typedef __attribute__((ext_vector_type(4))) unsigned short us4;

__device__ __forceinline__ unsigned short f2bf(float f) {
    __hip_bfloat16 h = __float2bfloat16(f);   // round-to-nearest
    return *reinterpret_cast<unsigned short*>(&h);
}

// ---------------------------------------------------------------------------
// init: zero out / barrier+shard state; convert W1,W2 to bf16^T
// ---------------------------------------------------------------------------
__global__ void init_kernel(float* __restrict__ out, int n_out,
                            float* __restrict__ zreg, int n_z,
                            const float* __restrict__ W1, const float* __restrict__ W2,
                            unsigned short* __restrict__ W1t,
                            unsigned short* __restrict__ W2t) {
    int i = blockIdx.x * blockDim.x + threadIdx.x;
    int stride = gridDim.x * blockDim.x;
    for (int j = i; j < n_out; j += stride) out[j] = 0.f;
    for (int j = i; j < n_z; j += stride) zreg[j] = 0.f;
    for (int j = i; j < C_DIM * C_DIM; j += stride) {   // W1t[n][k] = W1[k][n]
        int n = j >> 7, k = j & 127;
        W1t[j] = f2bf(W1[k * C_DIM + n]);
    }
    for (int j = i; j < C_DIM * K_DIM; j += stride) {   // W2t[n][k] = W2[k][n]
        int n = j >> 7, k = j & 127;
        W2t[j] = f2bf(W2[k * K_DIM + n]);
    }
}

// ---------------------------------------------------------------------------
// MFMA MLP: L = (relu(x@W1 + b1) @ W2 + b2) * sc, bf16 inputs / fp32 accum.
// (byte-identical to rounds 6/7/8)
// ---------------------------------------------------------------------------
__global__ __launch_bounds__(256, 4) void mlp_kernel(
    const float* __restrict__ x, const unsigned short* __restrict__ W1t,
    const float* __restrict__ b1, const unsigned short* __restrict__ W2t,
    const float* __restrict__ b2, const float* __restrict__ scal,
    float* __restrict__ Lg, int N, int ntiles) {
    __shared__ unsigned short sW1[C_DIM][WPAD];   // 34.0 KB  [n][k]
    __shared__ unsigned short sW2[K_DIM][WPAD];   //  8.5 KB  [n][k]
    __shared__ unsigned short sX[64][WPAD];       // 17.0 KB  [row][k] bf16
    __shared__ unsigned short sH[4][16][WPAD];    // 17.0 KB  per-wave h
    __shared__ float sB1[C_DIM];
    __shared__ float sB2[K_DIM];

    const int tid = threadIdx.x;
    for (int i = tid; i < C_DIM * 16; i += 256) {
        const int r = i >> 4, c8 = (i & 15) * 8;
        *(float4*)&sW1[r][c8] = *(const float4*)&W1t[r * C_DIM + c8];
    }
    for (int i = tid; i < K_DIM * 16; i += 256) {
        const int r = i >> 4, c8 = (i & 15) * 8;
        *(float4*)&sW2[r][c8] = *(const float4*)&W2t[r * C_DIM + c8];
    }
    if (tid < C_DIM) sB1[tid] = b1[tid];
    if (tid < K_DIM) sB2[tid] = b2[tid];
    const float sc = *scal;

    const int wave = tid >> 6;
    const int lane = tid & 63;
    const int lr = lane & 15;
    const int kg = lane >> 4;
    __syncthreads();

    for (int tile = blockIdx.x; tile < ntiles; tile += gridDim.x) {
        const int row0 = tile * 64;       // N % 64 == 0
        __syncthreads();
        for (int i = tid; i < 2048; i += 256) {
            const int r = i >> 5, c4 = (i & 31) * 4;
            const float4 v = *(const float4*)&x[(size_t)(row0 + r) * C_DIM + c4];
            us4 u;
            u.x = f2bf(v.x); u.y = f2bf(v.y); u.z = f2bf(v.z); u.w = f2bf(v.w);
            *(us4*)&sX[r][c4] = u;
        }
        __syncthreads();

        short8 a[4];
#pragma unroll
        for (int kt = 0; kt < 4; ++kt)
            a[kt] = *(const short8*)&sX[wave * 16 + lr][kt * 32 + kg * 8];
#pragma unroll
        for (int ct = 0; ct < 8; ++ct) {
            const float bv = sB1[ct * 16 + lr];
            f32x4 acc = {bv, bv, bv, bv};
#pragma unroll
            for (int kt = 0; kt < 4; ++kt) {
                const short8 b = *(const short8*)&sW1[ct * 16 + lr][kt * 32 + kg * 8];
                acc = __builtin_amdgcn_mfma_f32_16x16x32_bf16(a[kt], b, acc, 0, 0, 0);
            }
#pragma unroll
            for (int r = 0; r < 4; ++r)
                sH[wave][kg * 4 + r][ct * 16 + lr] = f2bf(fmaxf(acc[r], 0.f));
        }
        __syncthreads();

        short8 a2[4];
#pragma unroll
        for (int kt = 0; kt < 4; ++kt)
            a2[kt] = *(const short8*)&sH[wave][lr][kt * 32 + kg * 8];
#pragma unroll
        for (int ct = 0; ct < 2; ++ct) {
            const float bv = sB2[ct * 16 + lr];
            f32x4 acc = {bv, bv, bv, bv};
#pragma unroll
            for (int kt = 0; kt < 4; ++kt) {
                const short8 b = *(const short8*)&sW2[ct * 16 + lr][kt * 32 + kg * 8];
                acc = __builtin_amdgcn_mfma_f32_16x16x32_bf16(a2[kt], b, acc, 0, 0, 0);
            }
#pragma unroll
            for (int r = 0; r < 4; ++r) {
                const int g = row0 + wave * 16 + kg * 4 + r;
                Lg[(size_t)g * K_DIM + ct * 16 + lr] = acc[r] * sc;
            }
        }
    }
}

// ---------------------------------------------------------------------------
// persistent Sinkhorn v4: E-factorization + two-level tree barrier.
//   E_nj = exp(L_nj - M_n) once; per iter u' = E.w (w = e^{-v} in LDS),
//   r = 1/u', shard += E*r; root multiplies colsum = w_k * S_k.
// Barrier: wave-0-only. shard-adds by wave0 lanes -> single wave vmcnt(0) ->
// lane0 garr fetch_add (16/addr); group-last -> rarr (16/addr); root-last
// sums 16 shards, stores vglob[t], done[t]; group-lasts poll done ->
// gdone[t][g]; members poll gdone (<=16 pollers/addr). All per-t buffers.
// ---------------------------------------------------------------------------
__device__ __forceinline__ int bitrev5(int l) {
    return ((l & 1) << 4) | ((l & 2) << 2) | (l & 4) | ((l & 8) >> 2) |
           ((l & 16) >> 4);
}

#define FOLD_STAGE(M, HALF)                                   \
    {                                                         \
        const bool hi = (lane & (M)) != 0;                    \
        _Pragma("unroll")                                     \
        for (int j = 0; j < (HALF); ++j) {                    \
            const float give = hi ? p[j] : p[j + (HALF)];     \
            const float keep = hi ? p[j + (HALF)] : p[j];     \
            p[j] = keep + __shfl_xor(give, (M));              \
        }                                                     \
    }

__global__ __launch_bounds__(SK_THREADS) void sinkhorn_kernel(
    float* __restrict__ Lg, float* __restrict__ shards, float* __restrict__ vglob,
    int* __restrict__ garr, int* __restrict__ rarr, int* __restrict__ done,
    int* __restrict__ gdone, int N) {
    __shared__ float sv[K_DIM];              // running v
    __shared__ float sw[K_DIM];              // e^{-v}
    __shared__ float swsd[K_DIM];            // w19 * sd (final scale)
    __shared__ float swsum[SK_WAVES][K_DIM];
    const int tid = threadIdx.x;
    const int wave = tid >> 6;
    const int lane = tid & 63;
    const int g = blockIdx.x >> 4;           // group 0..15
    const size_t n = (size_t)blockIdx.x * SK_THREADS + tid;
    const bool valid = n < (size_t)N;
    const float log_tgt = __logf((float)N / (float)K_DIM);

    if (tid < K_DIM) { sv[tid] = 0.f; sw[tid] = 1.f; }

    // ---- prologue: E = exp(L - M) in registers (overwrites L) ----
    float E[K_DIM];
    if (valid) {
        const float4* Lr = (const float4*)(Lg + n * K_DIM);
#pragma unroll
        for (int j = 0; j < 8; ++j) {
            const float4 v = Lr[j];
            E[4 * j] = v.x; E[4 * j + 1] = v.y; E[4 * j + 2] = v.z; E[4 * j + 3] = v.w;
        }
        float M = E[0];
#pragma unroll
        for (int j = 1; j < K_DIM; ++j) M = fmaxf(M, E[j]);
#pragma unroll
        for (int j = 0; j < K_DIM; ++j) E[j] = __expf(E[j] - M);
    } else {
#pragma unroll
        for (int j = 0; j < K_DIM; ++j) E[j] = 0.f;
    }
    __syncthreads();

    float r_last = 0.f;
    for (int t = 1; t <= N_ITERS; ++t) {
        // u' = sum_j E_j * w_j ; r = 1/u' ; p_j = E_j * r
        float up = 0.f;
#pragma unroll
        for (int j = 0; j < K_DIM; ++j) up = fmaf(E[j], sw[j], up);
        float r = 0.f;
        if (valid) r = 1.0f / up;
        r_last = r;
        float p[K_DIM];
#pragma unroll
        for (int j = 0; j < K_DIM; ++j) p[j] = E[j] * r;

        FOLD_STAGE(1, 16)
        FOLD_STAGE(2, 8)
        FOLD_STAGE(4, 4)
        FOLD_STAGE(8, 2)
        FOLD_STAGE(16, 1)
        const float tot = p[0] + __shfl_xor(p[0], 32);
        if (lane < K_DIM) swsum[wave][bitrev5(lane)] = tot;
        __syncthreads();   // #1: swsum complete

        if (wave == 0) {
            if (lane < K_DIM) {
                float s_ = 0.f;
#pragma unroll
                for (int w = 0; w < SK_WAVES; ++w) s_ += swsum[w][lane];
                atomicAdd(&shards[((size_t)t * NGRP + g) * K_DIM + lane], s_);
            }
            // wave-level completion of all 32 shard adds
            asm volatile("s_waitcnt vmcnt(0)" ::: "memory");
            int is_gl = 0, is_rl = 0;
            if (lane == 0) {
                const int ga = __hip_atomic_fetch_add(&garr[t * NGRP + g], 1,
                                                      __ATOMIC_RELAXED,
                                                      __HIP_MEMORY_SCOPE_AGENT);
                is_gl = (ga == GSIZE - 1);
                if (is_gl) {
                    const int ra = __hip_atomic_fetch_add(&rarr[t], 1,
                                                          __ATOMIC_RELAXED,
                                                          __HIP_MEMORY_SCOPE_AGENT);
                    is_rl = (ra == NGRP - 1);
                }
            }
            is_gl = __shfl(is_gl, 0);
            is_rl = __shfl(is_rl, 0);
            if (is_rl) {
                if (lane < K_DIM) {
                    float cs = 0.f;
#pragma unroll
                    for (int gg = 0; gg < NGRP; ++gg)
                        cs += __hip_atomic_load(
                            &shards[((size_t)t * NGRP + gg) * K_DIM + lane],
                            __ATOMIC_RELAXED, __HIP_MEMORY_SCOPE_AGENT);
                    cs *= sw[lane];   // colsum_k = w_k * S_k
                    const float v = (t < N_ITERS) ? (__logf(cs) - log_tgt)
                                                  : ((float)N / (float)K_DIM) / cs;
                    __hip_atomic_store(&vglob[t * K_DIM + lane], v,
                                       __ATOMIC_RELAXED, __HIP_MEMORY_SCOPE_AGENT);
                }
                asm volatile("s_waitcnt vmcnt(0)" ::: "memory");
                if (lane == 0) {
                    __hip_atomic_store(done + t, 1, __ATOMIC_RELAXED,
                                       __HIP_MEMORY_SCOPE_AGENT);
                    __hip_atomic_store(&gdone[t * NGRP + g], 1, __ATOMIC_RELAXED,
                                       __HIP_MEMORY_SCOPE_AGENT);
                }
            } else if (is_gl) {
                if (lane == 0) {
                    while (__hip_atomic_load(done + t, __ATOMIC_RELAXED,
                                             __HIP_MEMORY_SCOPE_AGENT) == 0)
                        __builtin_amdgcn_s_sleep(1);
                    __hip_atomic_store(&gdone[t * NGRP + g], 1, __ATOMIC_RELAXED,
                                       __HIP_MEMORY_SCOPE_AGENT);
                }
            } else {
                if (lane == 0) {
                    while (__hip_atomic_load(&gdone[t * NGRP + g], __ATOMIC_RELAXED,
                                             __HIP_MEMORY_SCOPE_AGENT) == 0)
                        __builtin_amdgcn_s_sleep(1);
                }
            }
            // wave0 waits for lane0's poll (wave-uniform reconvergence), then
            // reads the broadcast value and updates v / w (or final scale).
            if (lane < K_DIM) {
                const float v = __hip_atomic_load(&vglob[t * K_DIM + lane],
                                                  __ATOMIC_RELAXED,
                                                  __HIP_MEMORY_SCOPE_AGENT);
                if (t < N_ITERS) {
                    sv[lane] += v;
                    sw[lane] = __expf(-sv[lane]);
                } else {
                    swsd[lane] = sw[lane] * v;   // w19_k * sd_k
                }
            }
        }
        __syncthreads();   // #2: sv/sw (or swsd) ready for all waves
    }

    // ---- epilogue: s = E_k * (w19_k * sd_k) * r20  (no exp needed) ----
    if (valid) {
        float4* Sr = (float4*)(Lg + n * K_DIM);
#pragma unroll
        for (int j = 0; j < 8; ++j) {
            float4 o;
            o.x = E[4 * j + 0] * swsd[4 * j + 0] * r_last;
            o.y = E[4 * j + 1] * swsd[4 * j + 1] * r_last;
            o.z = E[4 * j + 2] * swsd[4 * j + 2] * r_last;
            o.w = E[4 * j + 3] * swsd[4 * j + 3] * r_last;
            Sr[j] = o;
        }
    }
}

// ---------------------------------------------------------------------------
// final pooling: out[b,k,c] += s[n,k]*x[n,c], s precomputed in Sg (= Lg).
// (byte-identical to rounds 6/7/8)
// ---------------------------------------------------------------------------
#define PCHUNK 96
#define PCH_PER_BLOCK 4

__global__ __launch_bounds__(256) void pool_kernel(
    const float* __restrict__ x, const int* __restrict__ batch,
    const float* __restrict__ Sg, float* __restrict__ out, int N) {
    __shared__ float sx[PCHUNK][C_DIM];   // 48 KB
    __shared__ float ss[PCHUNK][K_DIM];   // 12 KB
    __shared__ int sb[PCHUNK];

    const int tid = threadIdx.x;
    const int k0 = (tid >> 5) * 4;
    const int c0 = (tid & 31) * 4;
    float acc[4][4];
#pragma unroll
    for (int i = 0; i < 4; ++i)
#pragma unroll
        for (int j = 0; j < 4; ++j) acc[i][j] = 0.f;

    int cur_b = -1;
    const int base0 = blockIdx.x * (PCHUNK * PCH_PER_BLOCK);

    for (int cc = 0; cc < PCH_PER_BLOCK; ++cc) {
        const int base = base0 + cc * PCHUNK;
        if (base >= N) break;  // block-uniform
        const int rows = min(PCHUNK, N - base);
        __syncthreads();
        {
            const float4* src = (const float4*)(x + (size_t)base * C_DIM);
            for (int i = tid; i < rows * (C_DIM / 4); i += 256)
                ((float4*)&sx[0][0])[i] = src[i];
            const float4* ssrc = (const float4*)(Sg + (size_t)base * K_DIM);
            for (int i = tid; i < rows * (K_DIM / 4); i += 256)
                ((float4*)&ss[0][0])[i] = ssrc[i];
        }
        if (tid < rows) sb[tid] = batch[base + tid];
        __syncthreads();

        for (int r = 0; r < rows; ++r) {
            const int b = sb[r];  // uniform across block
            if (b != cur_b) {
                if (cur_b >= 0) {
                    float* ob = out + ((size_t)cur_b * K_DIM + k0) * C_DIM + c0;
#pragma unroll
                    for (int i = 0; i < 4; ++i)
#pragma unroll
                        for (int j = 0; j < 4; ++j) {
                            atomicAdd(&ob[i * C_DIM + j], acc[i][j]);
                            acc[i][j] = 0.f;
                        }
                }
                cur_b = b;
            }
            const float4 sv = *(const float4*)&ss[r][k0];
            const float4 xv = *(const float4*)&sx[r][c0];
            const float sA[4] = {sv.x, sv.y, sv.z, sv.w};
            const float xA[4] = {xv.x, xv.y, xv.z, xv.w};
#pragma unroll
            for (int i = 0; i < 4; ++i)
#pragma unroll
                for (int j = 0; j < 4; ++j)
                    acc[i][j] = fmaf(sA[i], xA[j], acc[i][j]);
        }
    }
    if (cur_b >= 0) {
        float* ob = out + ((size_t)cur_b * K_DIM + k0) * C_DIM + c0;
#pragma unroll
        for (int i = 0; i < 4; ++i)
#pragma unroll
            for (int j = 0; j < 4; ++j) atomicAdd(&ob[i * C_DIM + j], acc[i][j]);
    }
}

// ---------------------------------------------------------------------------
extern "C" void kernel_launch(void* const* d_in, const int* in_sizes, int n_in,
                              void* d_out, int out_size, void* d_ws, size_t ws_size,
                              hipStream_t stream) {
    const float* x = (const float*)d_in[0];
    const int* batch = (const int*)d_in[1];
    const float* W1 = (const float*)d_in[2];
    const float* b1 = (const float*)d_in[3];
    const float* W2 = (const float*)d_in[4];
    const float* b2 = (const float*)d_in[5];
    const float* scal = (const float*)d_in[6];
    float* out = (float*)d_out;

    const int N = in_sizes[1];  // 200000

    // ws layout (4-byte words): L/S [N*32] | shards [21*16*32] | vglob [21*32]
    //   | garr [21*16 -> 352] | rarr [32] | done [32] | gdone [352]
    //   | W1t [16384 bf16] | W2t [4096 bf16]
    float* Lg = (float*)d_ws;
    float* shards = Lg + (size_t)N * K_DIM;
    const int n_shard_f = (N_ITERS + 1) * NGRP * K_DIM;     // 10752
    float* vglob = shards + n_shard_f;
    const int n_vglob = (N_ITERS + 1) * K_DIM;              // 672
    int* garr = (int*)(vglob + n_vglob);
    int* rarr = garr + 352;
    int* done = rarr + 32;
    int* gdone = done + 32;
    unsigned short* W1t = (unsigned short*)(gdone + 352);
    unsigned short* W2t = W1t + C_DIM * C_DIM;
    // contiguous zero region: shards + vglob + all counters (4B words)
    const int n_z = n_shard_f + n_vglob + 352 + 32 + 32 + 352;

    init_kernel<<<64, 256, 0, stream>>>(out, out_size, shards, n_z,
                                        W1, W2, W1t, W2t);

    const int ntiles = N / 64;  // 3125
    mlp_kernel<<<640, 256, 0, stream>>>(x, W1t, b1, W2t, b2, scal, Lg, N, ntiles);

    const int sblocks = NGRP * GSIZE;   // 256; 13 waves/block -> all resident
    sinkhorn_kernel<<<sblocks, SK_THREADS, 0, stream>>>(Lg, shards, vglob,
                                                        garr, rarr, done, gdone, N);

    const int pblocks = (N + PCHUNK * PCH_PER_BLOCK - 1) / (PCHUNK * PCH_PER_BLOCK);
    pool_kernel<<<pblocks, 256, 0, stream>>>(x, batch, Lg, out, N);
}

// Round 11
// 476.872 us; speedup vs baseline: 1.0421x; 1.0421x over previous
//
#include <hip/hip_runtime.h>
#include <hip/hip_bf16.h>

// Problem constants: N=200000, C=128, K=32, B=16, 20 Sinkhorn iters.
#define C_DIM 128
#define K_DIM 32
#define N_ITERS 20
#define WPAD 136   // bf16 row pad: 136*2B = 272B -> bank step 4/row (2-way = free)
#define SK_THREADS 832   // 13 waves
#define SK_WAVES 13
#define NGRP 16          // barrier tree: 16 groups x 16 blocks
#define GSIZE 16

typedef __attribute__((ext_vector_type(8))) short short8;      // 8 bf16 (4 VGPR) MFMA A/B frag
typedef __attribute__((ext_vector_type(4))) float f32x4;       // MFMA C/D frag

__device__ __forceinline__ unsigned short f2bf(float f) {
    __hip_bfloat16 h = __float2bfloat16(f);   // RTN (init only, cold path)
    return *reinterpret_cast<unsigned short*>(&h);
}

// fast bf16 convert: v_cvt_pk_bf16_f32 (1 inst / 2 values), dst.lo = src0
__device__ __forceinline__ unsigned short f2bf_fast(float f) {
    unsigned int u;
    asm("v_cvt_pk_bf16_f32 %0, %1, %1" : "=v"(u) : "v"(f));
    return (unsigned short)u;
}

__device__ __forceinline__ short8 pack8(float4 q0, float4 q1) {
    union { unsigned int u[4]; short8 s; } cv;
    asm("v_cvt_pk_bf16_f32 %0, %1, %2" : "=v"(cv.u[0]) : "v"(q0.x), "v"(q0.y));
    asm("v_cvt_pk_bf16_f32 %0, %1, %2" : "=v"(cv.u[1]) : "v"(q0.z), "v"(q0.w));
    asm("v_cvt_pk_bf16_f32 %0, %1, %2" : "=v"(cv.u[2]) : "v"(q1.x), "v"(q1.y));
    asm("v_cvt_pk_bf16_f32 %0, %1, %2" : "=v"(cv.u[3]) : "v"(q1.z), "v"(q1.w));
    return cv.s;
}

// ---------------------------------------------------------------------------
// init: zero out / barrier+shard state; convert W1,W2 to bf16^T
// ---------------------------------------------------------------------------
__global__ void init_kernel(float* __restrict__ out, int n_out,
                            float* __restrict__ zreg, int n_z,
                            const float* __restrict__ W1, const float* __restrict__ W2,
                            unsigned short* __restrict__ W1t,
                            unsigned short* __restrict__ W2t) {
    int i = blockIdx.x * blockDim.x + threadIdx.x;
    int stride = gridDim.x * blockDim.x;
    for (int j = i; j < n_out; j += stride) out[j] = 0.f;
    for (int j = i; j < n_z; j += stride) zreg[j] = 0.f;
    for (int j = i; j < C_DIM * C_DIM; j += stride) {   // W1t[n][k] = W1[k][n]
        int n = j >> 7, k = j & 127;
        W1t[j] = f2bf(W1[k * C_DIM + n]);
    }
    for (int j = i; j < C_DIM * K_DIM; j += stride) {   // W2t[n][k] = W2[k][n]
        int n = j >> 7, k = j & 127;
        W2t[j] = f2bf(W2[k * K_DIM + n]);
    }
}

// ---------------------------------------------------------------------------
// MFMA MLP v2: x loaded DIRECT global->regs (each row consumed by exactly one
// wave; LDS staging was pure overhead) + cvt_pk packing. sH is wave-private
// -> zero block barriers in the tile loop. LDS 60 KB -> 2 blocks/CU.
// Frag layout (m89-verified, validated rounds 6-9): A lane l: A[l&15][(l>>4)*8+j];
// B lane l: B[(l>>4)*8+j][l&15]; D lane l reg r: D[(l>>4)*4+r][l&15].
// ---------------------------------------------------------------------------
__global__ __launch_bounds__(256, 2) void mlp_kernel(
    const float* __restrict__ x, const unsigned short* __restrict__ W1t,
    const float* __restrict__ b1, const unsigned short* __restrict__ W2t,
    const float* __restrict__ b2, const float* __restrict__ scal,
    float* __restrict__ Lg, int N, int ntiles) {
    __shared__ unsigned short sW1[C_DIM][WPAD];   // 34.0 KB  [n][k]
    __shared__ unsigned short sW2[K_DIM][WPAD];   //  8.5 KB  [n][k]
    __shared__ unsigned short sH[4][16][WPAD];    // 17.0 KB  per-wave h
    __shared__ float sB1[C_DIM];
    __shared__ float sB2[K_DIM];

    const int tid = threadIdx.x;
    for (int i = tid; i < C_DIM * 16; i += 256) {
        const int r = i >> 4, c8 = (i & 15) * 8;
        *(float4*)&sW1[r][c8] = *(const float4*)&W1t[r * C_DIM + c8];
    }
    for (int i = tid; i < K_DIM * 16; i += 256) {
        const int r = i >> 4, c8 = (i & 15) * 8;
        *(float4*)&sW2[r][c8] = *(const float4*)&W2t[r * C_DIM + c8];
    }
    if (tid < C_DIM) sB1[tid] = b1[tid];
    if (tid < K_DIM) sB2[tid] = b2[tid];
    const float sc = *scal;

    const int wave = tid >> 6;
    const int lane = tid & 63;
    const int lr = lane & 15;
    const int kg = lane >> 4;
    __syncthreads();   // weights staged (only block-wide barrier)

    for (int tile = blockIdx.x; tile < ntiles; tile += gridDim.x) {
        const int row0 = tile * 64;       // N % 64 == 0

        // ---- layer 1: A-frags direct from global x, pack via cvt_pk ----
        const float* xr = x + (size_t)(row0 + wave * 16 + lr) * C_DIM + kg * 8;
        short8 a[4];
#pragma unroll
        for (int kt = 0; kt < 4; ++kt) {
            const float4 q0 = *(const float4*)(xr + kt * 32);
            const float4 q1 = *(const float4*)(xr + kt * 32 + 4);
            a[kt] = pack8(q0, q1);
        }
#pragma unroll
        for (int ct = 0; ct < 8; ++ct) {
            const float bv = sB1[ct * 16 + lr];
            f32x4 acc = {bv, bv, bv, bv};
#pragma unroll
            for (int kt = 0; kt < 4; ++kt) {
                const short8 b = *(const short8*)&sW1[ct * 16 + lr][kt * 32 + kg * 8];
                acc = __builtin_amdgcn_mfma_f32_16x16x32_bf16(a[kt], b, acc, 0, 0, 0);
            }
            // sH is wave-private: same-wave LDS program order suffices
#pragma unroll
            for (int r = 0; r < 4; ++r)
                sH[wave][kg * 4 + r][ct * 16 + lr] = f2bf_fast(fmaxf(acc[r], 0.f));
        }

        // ---- layer 2: L = (h@W2 + b2)*sc ----
        short8 a2[4];
#pragma unroll
        for (int kt = 0; kt < 4; ++kt)
            a2[kt] = *(const short8*)&sH[wave][lr][kt * 32 + kg * 8];
#pragma unroll
        for (int ct = 0; ct < 2; ++ct) {
            const float bv = sB2[ct * 16 + lr];
            f32x4 acc = {bv, bv, bv, bv};
#pragma unroll
            for (int kt = 0; kt < 4; ++kt) {
                const short8 b = *(const short8*)&sW2[ct * 16 + lr][kt * 32 + kg * 8];
                acc = __builtin_amdgcn_mfma_f32_16x16x32_bf16(a2[kt], b, acc, 0, 0, 0);
            }
#pragma unroll
            for (int r = 0; r < 4; ++r) {
                const int g = row0 + wave * 16 + kg * 4 + r;
                Lg[(size_t)g * K_DIM + ct * 16 + lr] = acc[r] * sc;
            }
        }
    }
}

// ---------------------------------------------------------------------------
// persistent Sinkhorn (split into [tb,te] parts for profiling visibility):
// E-factorization + two-level tree barrier (validated R9 dataflow).
// sv handoff through svbuf at part boundaries (kernel-boundary coherence).
// ---------------------------------------------------------------------------
__device__ __forceinline__ int bitrev5(int l) {
    return ((l & 1) << 4) | ((l & 2) << 2) | (l & 4) | ((l & 8) >> 2) |
           ((l & 16) >> 4);
}

#define FOLD_STAGE(M, HALF)                                   \
    {                                                         \
        const bool hi = (lane & (M)) != 0;                    \
        _Pragma("unroll")                                     \
        for (int j = 0; j < (HALF); ++j) {                    \
            const float give = hi ? p[j] : p[j + (HALF)];     \
            const float keep = hi ? p[j + (HALF)] : p[j];     \
            p[j] = keep + __shfl_xor(give, (M));              \
        }                                                     \
    }

__global__ __launch_bounds__(SK_THREADS) void sinkhorn_kernel(
    float* __restrict__ Lg, float* __restrict__ shards, float* __restrict__ vglob,
    int* __restrict__ garr, int* __restrict__ rarr, int* __restrict__ done,
    int* __restrict__ gdone, float* __restrict__ svbuf, int N, int tb, int te) {
    __shared__ float sv[K_DIM];              // running v
    __shared__ float sw[K_DIM];              // e^{-v}
    __shared__ float swsd[K_DIM];            // w19 * sd (final scale)
    __shared__ float swsum[SK_WAVES][K_DIM];
    const int tid = threadIdx.x;
    const int wave = tid >> 6;
    const int lane = tid & 63;
    const int g = blockIdx.x >> 4;           // group 0..15
    const size_t n = (size_t)blockIdx.x * SK_THREADS + tid;
    const bool valid = n < (size_t)N;
    const float log_tgt = __logf((float)N / (float)K_DIM);

    if (tid < K_DIM) {
        const float v0 = (tb == 1) ? 0.f : svbuf[tid];
        sv[tid] = v0;
        sw[tid] = __expf(-v0);
    }

    // ---- prologue: E = exp(L - M) in registers ----
    float E[K_DIM];
    if (valid) {
        const float4* Lr = (const float4*)(Lg + n * K_DIM);
#pragma unroll
        for (int j = 0; j < 8; ++j) {
            const float4 v = Lr[j];
            E[4 * j] = v.x; E[4 * j + 1] = v.y; E[4 * j + 2] = v.z; E[4 * j + 3] = v.w;
        }
        float M = E[0];
#pragma unroll
        for (int j = 1; j < K_DIM; ++j) M = fmaxf(M, E[j]);
#pragma unroll
        for (int j = 0; j < K_DIM; ++j) E[j] = __expf(E[j] - M);
    } else {
#pragma unroll
        for (int j = 0; j < K_DIM; ++j) E[j] = 0.f;
    }
    __syncthreads();

    float r_last = 0.f;
    for (int t = tb; t <= te; ++t) {
        float up = 0.f;
#pragma unroll
        for (int j = 0; j < K_DIM; ++j) up = fmaf(E[j], sw[j], up);
        float r = 0.f;
        if (valid) r = 1.0f / up;
        r_last = r;
        float p[K_DIM];
#pragma unroll
        for (int j = 0; j < K_DIM; ++j) p[j] = E[j] * r;

        FOLD_STAGE(1, 16)
        FOLD_STAGE(2, 8)
        FOLD_STAGE(4, 4)
        FOLD_STAGE(8, 2)
        FOLD_STAGE(16, 1)
        const float tot = p[0] + __shfl_xor(p[0], 32);
        if (lane < K_DIM) swsum[wave][bitrev5(lane)] = tot;
        __syncthreads();   // #1: swsum complete

        if (wave == 0) {
            if (lane < K_DIM) {
                float s_ = 0.f;
#pragma unroll
                for (int w = 0; w < SK_WAVES; ++w) s_ += swsum[w][lane];
                atomicAdd(&shards[((size_t)t * NGRP + g) * K_DIM + lane], s_);
            }
            asm volatile("s_waitcnt vmcnt(0)" ::: "memory");
            int is_gl = 0, is_rl = 0;
            if (lane == 0) {
                const int ga = __hip_atomic_fetch_add(&garr[t * NGRP + g], 1,
                                                      __ATOMIC_RELAXED,
                                                      __HIP_MEMORY_SCOPE_AGENT);
                is_gl = (ga == GSIZE - 1);
                if (is_gl) {
                    const int ra = __hip_atomic_fetch_add(&rarr[t], 1,
                                                          __ATOMIC_RELAXED,
                                                          __HIP_MEMORY_SCOPE_AGENT);
                    is_rl = (ra == NGRP - 1);
                }
            }
            is_gl = __shfl(is_gl, 0);
            is_rl = __shfl(is_rl, 0);
            if (is_rl) {
                if (lane < K_DIM) {
                    float cs = 0.f;
#pragma unroll
                    for (int gg = 0; gg < NGRP; ++gg)
                        cs += __hip_atomic_load(
                            &shards[((size_t)t * NGRP + gg) * K_DIM + lane],
                            __ATOMIC_RELAXED, __HIP_MEMORY_SCOPE_AGENT);
                    cs *= sw[lane];   // colsum_k = w_k * S_k
                    const float v = (t < N_ITERS) ? (__logf(cs) - log_tgt)
                                                  : ((float)N / (float)K_DIM) / cs;
                    __hip_atomic_store(&vglob[t * K_DIM + lane], v,
                                       __ATOMIC_RELAXED, __HIP_MEMORY_SCOPE_AGENT);
                }
                asm volatile("s_waitcnt vmcnt(0)" ::: "memory");
                if (lane == 0) {
                    __hip_atomic_store(done + t, 1, __ATOMIC_RELAXED,
                                       __HIP_MEMORY_SCOPE_AGENT);
                    __hip_atomic_store(&gdone[t * NGRP + g], 1, __ATOMIC_RELAXED,
                                       __HIP_MEMORY_SCOPE_AGENT);
                }
            } else if (is_gl) {
                if (lane == 0) {
                    while (__hip_atomic_load(done + t, __ATOMIC_RELAXED,
                                             __HIP_MEMORY_SCOPE_AGENT) == 0)
                        __builtin_amdgcn_s_sleep(1);
                    __hip_atomic_store(&gdone[t * NGRP + g], 1, __ATOMIC_RELAXED,
                                       __HIP_MEMORY_SCOPE_AGENT);
                }
            } else {
                if (lane == 0) {
                    while (__hip_atomic_load(&gdone[t * NGRP + g], __ATOMIC_RELAXED,
                                             __HIP_MEMORY_SCOPE_AGENT) == 0)
                        __builtin_amdgcn_s_sleep(1);
                }
            }
            if (lane < K_DIM) {
                const float v = __hip_atomic_load(&vglob[t * K_DIM + lane],
                                                  __ATOMIC_RELAXED,
                                                  __HIP_MEMORY_SCOPE_AGENT);
                if (t < N_ITERS) {
                    sv[lane] += v;
                    sw[lane] = __expf(-sv[lane]);
                } else {
                    swsd[lane] = sw[lane] * v;   // w19_k * sd_k
                }
            }
        }
        __syncthreads();   // #2: sv/sw (or swsd) ready for all waves
    }

    if (te < N_ITERS) {
        // part boundary: persist v for the next part (same value in all blocks)
        if (wave == 0 && lane < K_DIM) svbuf[lane] = sv[lane];
        return;
    }

    // ---- epilogue: s = E_k * (w19_k * sd_k) * r20 ----
    if (valid) {
        float4* Sr = (float4*)(Lg + n * K_DIM);
#pragma unroll
        for (int j = 0; j < 8; ++j) {
            float4 o;
            o.x = E[4 * j + 0] * swsd[4 * j + 0] * r_last;
            o.y = E[4 * j + 1] * swsd[4 * j + 1] * r_last;
            o.z = E[4 * j + 2] * swsd[4 * j + 2] * r_last;
            o.w = E[4 * j + 3] * swsd[4 * j + 3] * r_last;
            Sr[j] = o;
        }
    }
}

// ---------------------------------------------------------------------------
// final pooling: out[b,k,c] += s[n,k]*x[n,c], s precomputed in Sg (= Lg).
// PCH_PER_BLOCK 2 -> 1042 blocks (more latency hiding than R9's 521).
// ---------------------------------------------------------------------------
#define PCHUNK 96
#define PCH_PER_BLOCK 2

__global__ __launch_bounds__(256) void pool_kernel(
    const float* __restrict__ x, const int* __restrict__ batch,
    const float* __restrict__ Sg, float* __restrict__ out, int N) {
    __shared__ float sx[PCHUNK][C_DIM];   // 48 KB
    __shared__ float ss[PCHUNK][K_DIM];   // 12 KB
    __shared__ int sb[PCHUNK];

    const int tid = threadIdx.x;
    const int k0 = (tid >> 5) * 4;
    const int c0 = (tid & 31) * 4;
    float acc[4][4];
#pragma unroll
    for (int i = 0; i < 4; ++i)
#pragma unroll
        for (int j = 0; j < 4; ++j) acc[i][j] = 0.f;

    int cur_b = -1;
    const int base0 = blockIdx.x * (PCHUNK * PCH_PER_BLOCK);

    for (int cc = 0; cc < PCH_PER_BLOCK; ++cc) {
        const int base = base0 + cc * PCHUNK;
        if (base >= N) break;  // block-uniform
        const int rows = min(PCHUNK, N - base);
        __syncthreads();
        {
            const float4* src = (const float4*)(x + (size_t)base * C_DIM);
            for (int i = tid; i < rows * (C_DIM / 4); i += 256)
                ((float4*)&sx[0][0])[i] = src[i];
            const float4* ssrc = (const float4*)(Sg + (size_t)base * K_DIM);
            for (int i = tid; i < rows * (K_DIM / 4); i += 256)
                ((float4*)&ss[0][0])[i] = ssrc[i];
        }
        if (tid < rows) sb[tid] = batch[base + tid];
        __syncthreads();

        for (int r = 0; r < rows; ++r) {
            const int b = sb[r];  // uniform across block
            if (b != cur_b) {
                if (cur_b >= 0) {
                    float* ob = out + ((size_t)cur_b * K_DIM + k0) * C_DIM + c0;
#pragma unroll
                    for (int i = 0; i < 4; ++i)
#pragma unroll
                        for (int j = 0; j < 4; ++j) {
                            atomicAdd(&ob[i * C_DIM + j], acc[i][j]);
                            acc[i][j] = 0.f;
                        }
                }
                cur_b = b;
            }
            const float4 sv = *(const float4*)&ss[r][k0];
            const float4 xv = *(const float4*)&sx[r][c0];
            const float sA[4] = {sv.x, sv.y, sv.z, sv.w};
            const float xA[4] = {xv.x, xv.y, xv.z, xv.w};
#pragma unroll
            for (int i = 0; i < 4; ++i)
#pragma unroll
                for (int j = 0; j < 4; ++j)
                    acc[i][j] = fmaf(sA[i], xA[j], acc[i][j]);
        }
    }
    if (cur_b >= 0) {
        float* ob = out + ((size_t)cur_b * K_DIM + k0) * C_DIM + c0;
#pragma unroll
        for (int i = 0; i < 4; ++i)
#pragma unroll
            for (int j = 0; j < 4; ++j) atomicAdd(&ob[i * C_DIM + j], acc[i][j]);
    }
}

// ---------------------------------------------------------------------------
extern "C" void kernel_launch(void* const* d_in, const int* in_sizes, int n_in,
                              void* d_out, int out_size, void* d_ws, size_t ws_size,
                              hipStream_t stream) {
    const float* x = (const float*)d_in[0];
    const int* batch = (const int*)d_in[1];
    const float* W1 = (const float*)d_in[2];
    const float* b1 = (const float*)d_in[3];
    const float* W2 = (const float*)d_in[4];
    const float* b2 = (const float*)d_in[5];
    const float* scal = (const float*)d_in[6];
    float* out = (float*)d_out;

    const int N = in_sizes[1];  // 200000

    // ws layout (4-byte words): L/S [N*32] | shards [21*16*32] | vglob [21*32]
    //   | garr [352] | rarr [32] | done [32] | gdone [352] | svbuf [32]
    //   | W1t [16384 bf16] | W2t [4096 bf16]
    float* Lg = (float*)d_ws;
    float* shards = Lg + (size_t)N * K_DIM;
    const int n_shard_f = (N_ITERS + 1) * NGRP * K_DIM;     // 10752
    float* vglob = shards + n_shard_f;
    const int n_vglob = (N_ITERS + 1) * K_DIM;              // 672
    int* garr = (int*)(vglob + n_vglob);
    int* rarr = garr + 352;
    int* done = rarr + 32;
    int* gdone = done + 32;
    float* svbuf = (float*)(gdone + 352);
    unsigned short* W1t = (unsigned short*)(svbuf + 32);
    unsigned short* W2t = W1t + C_DIM * C_DIM;
    // contiguous zero region: shards..svbuf (4B words)
    const int n_z = n_shard_f + n_vglob + 352 + 32 + 32 + 352 + 32;

    init_kernel<<<64, 256, 0, stream>>>(out, out_size, shards, n_z,
                                        W1, W2, W1t, W2t);

    const int ntiles = N / 64;  // 3125
    mlp_kernel<<<768, 256, 0, stream>>>(x, W1t, b1, W2t, b2, scal, Lg, N, ntiles);

    const int sblocks = NGRP * GSIZE;   // 256; 13 waves/block -> all resident
    sinkhorn_kernel<<<sblocks, SK_THREADS, 0, stream>>>(
        Lg, shards, vglob, garr, rarr, done, gdone, svbuf, N, 1, 10);
    sinkhorn_kernel<<<sblocks, SK_THREADS, 0, stream>>>(
        Lg, shards, vglob, garr, rarr, done, gdone, svbuf, N, 11, 20);

    const int pblocks = (N + PCHUNK * PCH_PER_BLOCK - 1) / (PCHUNK * PCH_PER_BLOCK);
    pool_kernel<<<pblocks, 256, 0, stream>>>(x, batch, Lg, out, N);
}